// Round 6
// baseline (345.397 us; speedup 1.0000x reference)
//
#include <hip/hip_runtime.h>
#include <hip/hip_bf16.h>
#include <hip/hip_fp16.h>
#include <math.h>

// Problem constants
#define BATCH   8
#define LSEQ    4096      // 64*64
#define CMODEL  128
#define DIN     256
#define NSTATE  16
#define RRANK   8
#define NCH     128       // chunks per sequence
#define TCH     32        // timesteps per chunk (NCH*TCH == LSEQ)

typedef __attribute__((ext_vector_type(8))) short short8;
typedef __attribute__((ext_vector_type(4))) float f32x4;
typedef __attribute__((ext_vector_type(2))) float f32x2;

__device__ __forceinline__ float sigmoid_fast(float x) {
    return __builtin_amdgcn_rcpf(1.0f + __expf(-x));
}
__device__ __forceinline__ float silu_fast(float x) { return x * sigmoid_fast(x); }
__device__ __forceinline__ float softplus_fast(float x) {
    return fmaxf(x, 0.0f) + __logf(1.0f + __expf(-fabsf(x)));
}
__device__ __forceinline__ float bf2f(unsigned short u) {
    return __uint_as_float(((unsigned)u) << 16);
}
// packed fp32x2 -> bf16x2 (v_cvt_pk_bf16_f32); a -> low, b -> high
__device__ __forceinline__ unsigned pk2bf(float a, float b) {
    __hip_bfloat162 t = __float22bfloat162_rn(make_float2(a, b));
    unsigned r;
    __builtin_memcpy(&r, &t, 4);
    return r;
}
__device__ __forceinline__ unsigned short f2bf1(float v) {   // 1-op scalar cvt
    return (unsigned short)pk2bf(v, v);
}

// dA2[j] = {exp(dtv*A[2j]), exp(dtv*A[2j+1])}; fast path via packed mul chain.
__device__ __forceinline__ void dA_powers2(float dtv, const float* A, bool fast,
                                           f32x2* dA2)
{
    if (fast) {
        float e1 = __expf(dtv * A[0]);
        float e2 = e1 * e1;
        dA2[0] = (f32x2){e1, e2};
        f32x2 e2s = (f32x2){e2, e2};
        #pragma unroll
        for (int j = 1; j < 8; ++j) dA2[j] = dA2[j-1] * e2s;
    } else {
        #pragma unroll
        for (int j = 0; j < 8; ++j)
            dA2[j] = (f32x2){__expf(dtv * A[2*j]), __expf(dtv * A[2*j+1])};
    }
}

#define LSTR 72   // LDS row stride (bf16 units): 64 data + 8 pad; 2-way max = free
#define YSTR 264  // full-width y/xc tile stride (256 data + 8 pad)

// ---------------------------------------------------------------------------
// K0: weight transposes (tiny) + W_x^T + part zero. grid 26, block 256
// ---------------------------------------------------------------------------
__device__ __forceinline__ void tr64_bf(const float* __restrict__ src, int lds,
                                        int r0, int c0,
                                        unsigned short* __restrict__ dst, int ldd)
{
    __shared__ float ts[64][65];
    const int tid = threadIdx.x;
    #pragma unroll
    for (int it = 0; it < 4; ++it) {
        int slot = tid + it * 256;
        int i = slot >> 4, j4 = slot & 15;
        float4 v = *(const float4*)&src[(size_t)(r0 + i) * lds + c0 + j4 * 4];
        ts[i][j4*4+0] = v.x; ts[i][j4*4+1] = v.y;
        ts[i][j4*4+2] = v.z; ts[i][j4*4+3] = v.w;
    }
    __syncthreads();
    #pragma unroll
    for (int it = 0; it < 4; ++it) {
        int slot = tid + it * 256;
        int row = slot >> 4, c4 = slot & 15;
        unsigned p0 = pk2bf(ts[c4*4+0][row], ts[c4*4+1][row]);
        unsigned p1 = pk2bf(ts[c4*4+2][row], ts[c4*4+3][row]);
        unsigned long long u = (unsigned long long)p0 | ((unsigned long long)p1 << 32);
        *(unsigned long long*)&dst[(size_t)(c0 + row) * ldd + r0 + c4 * 4] = u;
    }
}

__global__ __launch_bounds__(256) void k0_setup(
    const float* __restrict__ W_in, const float* __restrict__ W_out,
    const float* __restrict__ W_x,
    unsigned short* __restrict__ wtin, unsigned short* __restrict__ wtout,
    unsigned short* __restrict__ wxt, float* __restrict__ part)
{
    const int bid = blockIdx.x;
    if (bid < 16) {
        int ct = bid >> 3, jt = bid & 7;
        tr64_bf(W_in, 512, ct * 64, jt * 64, wtin, 128);
    } else if (bid < 24) {
        int t3 = bid - 16;
        int kt = t3 >> 1, ct = t3 & 1;
        tr64_bf(W_out, 128, kt * 64, ct * 64, wtout, 256);
    } else if (bid == 24) {
        // W_x [256 k][40 j] -> wxt [48 j][256 k] bf16 (rows 40..47 zero)
        for (int idx = threadIdx.x; idx < 48 * 256; idx += 256) {
            int j = idx >> 8, k = idx & 255;
            float v = (j < 40) ? W_x[k * 40 + j] : 0.0f;
            wxt[(size_t)j * 256 + k] = f2bf1(v);
        }
    } else {
        if (threadIdx.x < 64) part[threadIdx.x] = 0.0f;
    }
}

// ---------------------------------------------------------------------------
// K1 (MFMA bf16): xz = x @ W_in. 128(l) x 256(j) tile, 8 waves, K=128 in
// chunks of 64. B-frags read direct from global wtin (L2-hot, no LDS).
// grid (256, 2), block 512
// ---------------------------------------------------------------------------
__global__ __launch_bounds__(512) void k1_gemm_in(
    const float* __restrict__ x_hsi, const unsigned short* __restrict__ wtin,
    unsigned short* __restrict__ xhbf, unsigned short* __restrict__ zbf)
{
    __shared__ __align__(16) unsigned short Abf[128 * LSTR];   // rows = l
    const int tid = threadIdx.x;
    const int R0  = blockIdx.x * 128;         // global row (b*L + l)
    const int b   = R0 >> 12;
    const int l0  = R0 & 4095;
    const int jbase = blockIdx.y * 256;

    const int w    = tid >> 6;                // 0..7
    const int lane = tid & 63;
    const int lm   = lane & 15;
    const int q    = lane >> 4;
    const int mbase = (w & 1) * 64;           // l-quadrant
    const int nbase = (w >> 1) * 64;          // j-quadrant (0..192)

    f32x4 acc[4][4];
    #pragma unroll
    for (int i = 0; i < 4; ++i)
        #pragma unroll
        for (int j = 0; j < 4; ++j) acc[i][j] = (f32x4){0.f, 0.f, 0.f, 0.f};

    const int cq = tid & 15;                  // c-quad within chunk (16*4=64)
    const int lq = tid >> 4;                  // l-quad (32*4=128)

    for (int kc = 0; kc < 128; kc += 64) {
        __syncthreads();
        // stage A: x[c][l] -> Abf[l][c_local] (transpose + packed cvt)
        {
            float v[4][4];
            #pragma unroll
            for (int t = 0; t < 4; ++t) {
                float4 f = *(const float4*)&x_hsi[((b * 128 + kc + cq * 4 + t) << 12) + l0 + lq * 4];
                v[t][0] = f.x; v[t][1] = f.y; v[t][2] = f.z; v[t][3] = f.w;
            }
            #pragma unroll
            for (int i = 0; i < 4; ++i) {
                unsigned p0 = pk2bf(v[0][i], v[1][i]);
                unsigned p1 = pk2bf(v[2][i], v[3][i]);
                unsigned long long u = (unsigned long long)p0 | ((unsigned long long)p1 << 32);
                *(unsigned long long*)&Abf[(lq * 4 + i) * LSTR + cq * 4] = u;
            }
        }
        __syncthreads();
        #pragma unroll
        for (int kt = 0; kt < 2; ++kt) {
            short8 af[4], bfr[4];
            #pragma unroll
            for (int mt = 0; mt < 4; ++mt)
                af[mt] = *(const short8*)&Abf[(mbase + mt * 16 + lm) * LSTR + kt * 32 + q * 8];
            #pragma unroll
            for (int nt = 0; nt < 4; ++nt)
                bfr[nt] = *(const short8*)&wtin[(size_t)(jbase + nbase + nt * 16 + lm) * 128 + kc + kt * 32 + q * 8];
            #pragma unroll
            for (int mt = 0; mt < 4; ++mt)
                #pragma unroll
                for (int nt = 0; nt < 4; ++nt)
                    acc[mt][nt] = __builtin_amdgcn_mfma_f32_16x16x32_bf16(
                        af[mt], bfr[nt], acc[mt][nt], 0, 0, 0);
        }
    }

    const bool is_xh = (jbase == 0);
    #pragma unroll
    for (int mt = 0; mt < 4; ++mt) {
        #pragma unroll
        for (int r = 0; r < 4; ++r) {
            int row = R0 + mbase + mt * 16 + q * 4 + r;
            #pragma unroll
            for (int nt = 0; nt < 4; ++nt) {
                int col = nbase + nt * 16 + lm;     // 0..255
                float val = acc[mt][nt][r];
                if (is_xh) xhbf[row * 256 + col] = f2bf1(val);
                else       zbf[row * 256 + col]  = f2bf1(silu_fast(val));
            }
        }
    }
}

// ---------------------------------------------------------------------------
// K46: conv_silu(xh) -> xcb (LDS bf16 + global xcbf)
//      -> x_dbl via MFMA (A = xcb LDS, B = wxt global direct) -> global xdbl.
// One block = one chunk (32 t x 256 d). grid (NCH, BATCH), block 256.
// ---------------------------------------------------------------------------
__global__ __launch_bounds__(256) void k46_conv_xdbl(
    const unsigned short* __restrict__ xhbf, const float* __restrict__ conv_w,
    const float* __restrict__ conv_b, const unsigned short* __restrict__ wxt,
    float* __restrict__ xdbl, unsigned short* __restrict__ xcbf)
{
    __shared__ float cw0[256], cw1[256], cbs[256];
    __shared__ __align__(16) unsigned short xcb[TCH][YSTR]; // conv tile bf16
    const int tid = threadIdx.x;
    const int chunk = blockIdx.x;
    const int b = blockIdx.y;
    const int R0 = b * LSEQ + chunk * TCH;

    cw0[tid] = conv_w[2 * tid];
    cw1[tid] = conv_w[2 * tid + 1];
    cbs[tid] = conv_b[tid];
    __syncthreads();   // cw ready

    // ---- conv + silu: whole 32 x 256 tile -> xcb (bf16) + xcbf (global) ----
    #pragma unroll
    for (int it = 0; it < 8; ++it) {
        int idx = tid + it * 256;            // 32 rows x 64 quads
        int r = idx >> 6, qq = idx & 63;
        int row = R0 + r;
        int dd = qq * 4;
        ushort4 cu = *(const ushort4*)&xhbf[(size_t)row * 256 + dd];
        float cur[4] = {bf2f(cu.x), bf2f(cu.y), bf2f(cu.z), bf2f(cu.w)};
        float pv[4] = {0.f, 0.f, 0.f, 0.f};
        if ((row & 4095) != 0) {
            ushort4 pu = *(const ushort4*)&xhbf[(size_t)(row - 1) * 256 + dd];
            pv[0] = bf2f(pu.x); pv[1] = bf2f(pu.y);
            pv[2] = bf2f(pu.z); pv[3] = bf2f(pu.w);
        }
        float o[4];
        #pragma unroll
        for (int e = 0; e < 4; ++e)
            o[e] = silu_fast(pv[e] * cw0[dd+e] + cur[e] * cw1[dd+e] + cbs[dd+e]);
        unsigned p0 = pk2bf(o[0], o[1]), p1 = pk2bf(o[2], o[3]);
        unsigned long long u = (unsigned long long)p0 | ((unsigned long long)p1 << 32);
        *(unsigned long long*)&xcb[r][dd] = u;
        *(unsigned long long*)&xcbf[(size_t)row * 256 + dd] = u;
    }
    __syncthreads();

    // ---- x_dbl = xcb @ W_x via MFMA (out 32 x 40, K = 256) ----
    // tiles: wave0: m0 n{0,1}; wave1: m1 n{0,1}; wave2: m0 n{2}; wave3: m1 n{2}
    const int w    = tid >> 6;
    const int lane = tid & 63;
    const int lm   = lane & 15;
    const int q    = lane >> 4;
    const int mt  = w & 1;
    const int nlo = (w < 2) ? 0 : 2;
    const int nn  = (w < 2) ? 2 : 1;
    f32x4 macc[2];
    macc[0] = (f32x4){0.f,0.f,0.f,0.f};
    macc[1] = (f32x4){0.f,0.f,0.f,0.f};
    for (int kc = 0; kc < 256; kc += 32) {
        short8 af = *(const short8*)&xcb[mt * 16 + lm][kc + q * 8];
        #pragma unroll
        for (int t = 0; t < 2; ++t) {
            if (t < nn) {
                short8 bfr = *(const short8*)&wxt[(size_t)((nlo + t) * 16 + lm) * 256 + kc + q * 8];
                macc[t] = __builtin_amdgcn_mfma_f32_16x16x32_bf16(
                    af, bfr, macc[t], 0, 0, 0);
            }
        }
    }
    #pragma unroll
    for (int t = 0; t < 2; ++t) {
        if (t < nn) {
            #pragma unroll
            for (int r = 0; r < 4; ++r) {
                int row = mt * 16 + q * 4 + r;
                int col = (nlo + t) * 16 + lm;
                if (col < 40)
                    xdbl[(size_t)(R0 + row) * 40 + col] = macc[t][r];
            }
        }
    }
}

// ---------------------------------------------------------------------------
// K6: scan pass 1 (h_in = 0). Zero LDS. Group-8 double-buffered prefetch of
// the per-lane xcbf loads; xdbl rows wave-uniform (scalar loads). Stores
// dtvh (fp16) for pass 3. grid (NCH, BATCH), block 256.
// ---------------------------------------------------------------------------
__global__ __launch_bounds__(256) void k6_scan1(
    const unsigned short* __restrict__ xcbf, const float* __restrict__ xdbl,
    const float* __restrict__ W_dt, const float* __restrict__ b_dt,
    const float* __restrict__ A_log,
    float* __restrict__ hend, float* __restrict__ dtsg,
    __half* __restrict__ dtvh)
{
    const int d = threadIdx.x;
    const int chunk = blockIdx.x;
    const int b = blockIdx.y;
    const int t0 = b * LSEQ + chunk * TCH;

    float A[16];
    #pragma unroll
    for (int qq = 0; qq < 4; ++qq) {
        float4 al = *(const float4*)&A_log[d * 16 + qq * 4];
        A[qq*4+0] = -__expf(al.x); A[qq*4+1] = -__expf(al.y);
        A[qq*4+2] = -__expf(al.z); A[qq*4+3] = -__expf(al.w);
    }
    bool fast = true;
    #pragma unroll
    for (int n = 1; n < 16; ++n)
        fast = fast && (fabsf(A[n] - (n + 1) * A[0]) <= 1e-4f * fabsf(A[n]) + 1e-7f);
    float wdt[8];
    #pragma unroll
    for (int r = 0; r < 8; ++r) wdt[r] = W_dt[r * 256 + d];
    const float bdt = b_dt[d];

    // prefetch pipeline: groups of 8 timesteps, double-buffered
    unsigned short xc[2][8];
    #pragma unroll
    for (int i = 0; i < 8; ++i)
        xc[0][i] = xcbf[(size_t)(t0 + i) * 256 + d];

    f32x2 h2[8];
    #pragma unroll
    for (int j = 0; j < 8; ++j) h2[j] = (f32x2){0.f, 0.f};
    float dtsum = 0.f;

    #pragma unroll
    for (int g = 0; g < 4; ++g) {
        if (g < 3) {
            #pragma unroll
            for (int i = 0; i < 8; ++i)
                xc[(g + 1) & 1][i] = xcbf[(size_t)(t0 + (g + 1) * 8 + i) * 256 + d];
        }
        #pragma unroll
        for (int i = 0; i < 8; ++i) {
            const int tt = g * 8 + i;
            const int row = t0 + tt;
            float xcv = bf2f(xc[g & 1][i]);

            const float* xr = &xdbl[(size_t)row * 40];   // wave-uniform
            float dl[8], Bv[16];
            *(float4*)&dl[0] = *(const float4*)&xr[0];
            *(float4*)&dl[4] = *(const float4*)&xr[4];
            *(float4*)&Bv[0]  = *(const float4*)&xr[8];
            *(float4*)&Bv[4]  = *(const float4*)&xr[12];
            *(float4*)&Bv[8]  = *(const float4*)&xr[16];
            *(float4*)&Bv[12] = *(const float4*)&xr[20];

            float dtr = bdt;
            #pragma unroll
            for (int r = 0; r < 8; ++r) dtr = fmaf(dl[r], wdt[r], dtr);
            float dtv = softplus_fast(dtr);
            dtsum += dtv;
            float dtx = dtv * xcv;
            dtvh[(size_t)row * 256 + d] = __float2half(dtv);

            f32x2 dA2[8];
            dA_powers2(dtv, A, fast, dA2);
            f32x2 dtx2 = (f32x2){dtx, dtx};
            #pragma unroll
            for (int j = 0; j < 8; ++j) {
                f32x2 Bt2 = (f32x2){Bv[2*j], Bv[2*j+1]};
                h2[j] = dA2[j] * h2[j] + dtx2 * Bt2;
            }
        }
    }

    const float* hf = (const float*)h2;
    const int base = ((b * NCH + chunk) * 256 + d) * 16;
    #pragma unroll
    for (int qq = 0; qq < 4; ++qq)
        *(float4*)&hend[base + qq * 4] = make_float4(hf[qq*4], hf[qq*4+1], hf[qq*4+2], hf[qq*4+3]);
    dtsg[(b * NCH + chunk) * 256 + d] = dtsum;
}

// ---------------------------------------------------------------------------
// Scan pass 2: sequential combine with P(c) = exp(dtsum(c)*A[n]) on the fly;
// hx: hend -> hin in-place. 8-deep prefetch, NCH/8 = 16 groups.
// grid 128, block 256
// ---------------------------------------------------------------------------
__global__ __launch_bounds__(256) void k7_combine(
    const float* __restrict__ dtsg, const float* __restrict__ A_log,
    float* __restrict__ hx)
{
    const int idx = blockIdx.x * 256 + threadIdx.x;   // b*4096 + d*16 + n
    const int b = idx >> 12;
    const int rem = idx & 4095;
    const int d = rem >> 4, n = rem & 15;
    const float An = -__expf(A_log[d * 16 + n]);
    const int base = b * NCH * 4096 + rem;            // hx index, +4096/chunk
    const int sbase = b * NCH * 256 + d;              // dtsg index, +256/chunk
    float h = 0.f;
    float Sb[8], Eb[8];
    #pragma unroll
    for (int j = 0; j < 8; ++j) {
        Sb[j] = dtsg[sbase + j * 256];
        Eb[j] = hx[base + j * 4096];
    }
    for (int g = 0; g < NCH / 8; ++g) {
        const int o  = base + g * 32768;
        const int so = sbase + g * 2048;
        float Sn[8] = {0,0,0,0,0,0,0,0}, En[8] = {0,0,0,0,0,0,0,0};
        if (g < NCH / 8 - 1) {
            #pragma unroll
            for (int j = 0; j < 8; ++j) {
                Sn[j] = dtsg[so + 2048 + j * 256];
                En[j] = hx[o + 32768 + j * 4096];
            }
        }
        #pragma unroll
        for (int j = 0; j < 8; ++j) {
            hx[o + j * 4096] = h;
            float P = __expf(Sb[j] * An);
            h = fmaf(P, h, Eb[j]);
        }
        #pragma unroll
        for (int j = 0; j < 8; ++j) { Sb[j] = Sn[j]; Eb[j] = En[j]; }
    }
}

// ---------------------------------------------------------------------------
// K89 (fused): scan pass 3 (dtv from dtvh fp16; group-8 prefetch of
// xcbf/zbf/dtvh; B/C via wave-uniform loads) -> y*silu(z) into Ybf LDS tile
// (bf16) -> MFMA out-GEMM with A-frags direct from global wtout + fused GN
// partials. One block = one chunk (32 t x 256 d). grid (NCH, BATCH),
// block 256. launch_bounds(256,4) pins VGPR <= 128 (grid gives 4 blocks/CU).
// ---------------------------------------------------------------------------
__global__ __launch_bounds__(256, 4) void k89_scan2_gemm_out(
    const unsigned short* __restrict__ xcbf, const float* __restrict__ xdbl,
    const __half* __restrict__ dtvh, const float* __restrict__ A_log,
    const float* __restrict__ Dvec, const float* __restrict__ hin,
    const unsigned short* __restrict__ zbf,
    const unsigned short* __restrict__ wtout,
    unsigned short* __restrict__ out_bf, float* __restrict__ part)
{
    __shared__ __align__(16) unsigned short Ybf[TCH][YSTR];    // y tile (rows=l)
    __shared__ float pred[8];
    const int tid = threadIdx.x;
    const int chunk = blockIdx.x;
    const int b = blockIdx.y;
    const int t0 = b * LSEQ + chunk * TCH;

    if (tid < 8) pred[tid] = 0.0f;

    const int d = tid;
    float A[16];
    #pragma unroll
    for (int qq = 0; qq < 4; ++qq) {
        float4 al = *(const float4*)&A_log[d * 16 + qq * 4];
        A[qq*4+0] = -__expf(al.x); A[qq*4+1] = -__expf(al.y);
        A[qq*4+2] = -__expf(al.z); A[qq*4+3] = -__expf(al.w);
    }
    bool fast = true;
    #pragma unroll
    for (int n = 1; n < 16; ++n)
        fast = fast && (fabsf(A[n] - (n + 1) * A[0]) <= 1e-4f * fabsf(A[n]) + 1e-7f);
    const float Dd = Dvec[d];

    f32x2 h2[8];
    {
        const int hbase = ((b * NCH + chunk) * 256 + d) * 16;
        float hf[16];
        #pragma unroll
        for (int qq = 0; qq < 4; ++qq) {
            float4 hv = *(const float4*)&hin[hbase + qq * 4];
            hf[qq*4+0] = hv.x; hf[qq*4+1] = hv.y; hf[qq*4+2] = hv.z; hf[qq*4+3] = hv.w;
        }
        #pragma unroll
        for (int j = 0; j < 8; ++j) h2[j] = (f32x2){hf[2*j], hf[2*j+1]};
    }

    // prefetch pipeline: groups of 8 timesteps, double-buffered
    const unsigned short* dth = (const unsigned short*)dtvh;
    unsigned short xc[2][8], zb[2][8], dt[2][8];
    #pragma unroll
    for (int i = 0; i < 8; ++i) {
        size_t gi = (size_t)(t0 + i) * 256 + d;
        xc[0][i] = xcbf[gi];
        zb[0][i] = zbf[gi];
        dt[0][i] = dth[gi];
    }

    // ---- scan pass 3: y -> Ybf (bf16, already gated by silu(z)) ----
    #pragma unroll
    for (int g = 0; g < 4; ++g) {
        if (g < 3) {
            #pragma unroll
            for (int i = 0; i < 8; ++i) {
                size_t gi = (size_t)(t0 + (g + 1) * 8 + i) * 256 + d;
                xc[(g + 1) & 1][i] = xcbf[gi];
                zb[(g + 1) & 1][i] = zbf[gi];
                dt[(g + 1) & 1][i] = dth[gi];
            }
        }
        #pragma unroll
        for (int i = 0; i < 8; ++i) {
            const int tt = g * 8 + i;
            const int row = t0 + tt;
            float xcv = bf2f(xc[g & 1][i]);
            __half hv;
            __builtin_memcpy(&hv, &dt[g & 1][i], 2);
            float dtv = __half2float(hv);
            float dtx = dtv * xcv;

            const float* xr = &xdbl[(size_t)row * 40];   // wave-uniform
            float Bv[16], Cv[16];
            *(float4*)&Bv[0]  = *(const float4*)&xr[8];
            *(float4*)&Bv[4]  = *(const float4*)&xr[12];
            *(float4*)&Bv[8]  = *(const float4*)&xr[16];
            *(float4*)&Bv[12] = *(const float4*)&xr[20];
            *(float4*)&Cv[0]  = *(const float4*)&xr[24];
            *(float4*)&Cv[4]  = *(const float4*)&xr[28];
            *(float4*)&Cv[8]  = *(const float4*)&xr[32];
            *(float4*)&Cv[12] = *(const float4*)&xr[36];

            f32x2 dA2[8];
            dA_powers2(dtv, A, fast, dA2);
            f32x2 dtx2 = (f32x2){dtx, dtx};
            f32x2 yv2 = (f32x2){0.f, 0.f};
            #pragma unroll
            for (int j = 0; j < 8; ++j) {
                f32x2 Bt2 = (f32x2){Bv[2*j], Bv[2*j+1]};
                f32x2 Ct2 = (f32x2){Cv[2*j], Cv[2*j+1]};
                h2[j] = dA2[j] * h2[j] + dtx2 * Bt2;
                yv2 = yv2 + h2[j] * Ct2;
            }
            float yv = yv2.x + yv2.y;
            yv = fmaf(Dd, xcv, yv);
            Ybf[tt][d] = f2bf1(yv * bf2f(zb[g & 1][i]));
        }
    }
    __syncthreads();

    // ---- MFMA out-GEMM: out[c][l] = sum_k wtout[c][k] * y[l][k] ----
    // A-frags direct from global wtout (L2-hot); B-frags from Ybf LDS.
    const int w    = tid >> 6;
    const int lane = tid & 63;
    const int lm   = lane & 15;
    const int q    = lane >> 4;
    const int mbase = (w & 1) * 64;           // c-half
    const int nbase = (w >> 1) * 16;          // l-half (of 32)

    f32x4 acc[4];
    #pragma unroll
    for (int i = 0; i < 4; ++i) acc[i] = (f32x4){0.f, 0.f, 0.f, 0.f};

    for (int ks = 0; ks < 256; ks += 32) {
        short8 bfr = *(const short8*)&Ybf[nbase + lm][ks + q * 8];
        #pragma unroll
        for (int mt = 0; mt < 4; ++mt) {
            short8 af = *(const short8*)&wtout[(size_t)(mbase + mt * 16 + lm) * 256 + ks + q * 8];
            acc[mt] = __builtin_amdgcn_mfma_f32_16x16x32_bf16(
                af, bfr, acc[mt], 0, 0, 0);
        }
    }

    const int l0 = chunk * TCH;
    #pragma unroll
    for (int mt = 0; mt < 4; ++mt) {
        #pragma unroll
        for (int r = 0; r < 4; ++r) {
            int c = mbase + mt * 16 + q * 4 + r;
            long obase = (long)(b * 128 + c) * 4096 + l0;
            out_bf[obase + nbase + lm] = f2bf1(acc[mt][r]);
        }
    }

    // fused GroupNorm partial sums (fp32 from accumulators)
    float s0 = 0.f, q0 = 0.f, s1 = 0.f, q1 = 0.f;
    #pragma unroll
    for (int mt = 0; mt < 4; ++mt)
        #pragma unroll
        for (int r = 0; r < 4; ++r) {
            float v = acc[mt][r];
            if (mt < 2) { s0 += v; q0 += v * v; }
            else        { s1 += v; q1 += v * v; }
        }
    #pragma unroll
    for (int off = 32; off > 0; off >>= 1) {
        s0 += __shfl_down(s0, off, 64);
        q0 += __shfl_down(q0, off, 64);
        s1 += __shfl_down(s1, off, 64);
        q1 += __shfl_down(q1, off, 64);
    }
    if (lane == 0) {
        int g0 = mbase >> 5;                  // 0 or 2
        atomicAdd(&pred[g0 * 2],           s0);
        atomicAdd(&pred[g0 * 2 + 1],       q0);
        atomicAdd(&pred[(g0 + 1) * 2],     s1);
        atomicAdd(&pred[(g0 + 1) * 2 + 1], q1);
    }
    __syncthreads();
    if (tid < 8) atomicAdd(&part[b * 8 + tid], pred[tid]);
}

// K10c: apply GN + silu + residual (stat from part; out_bf bf16).
// grid 4096, block 256
__global__ __launch_bounds__(256) void k10c_apply(
    const unsigned short* __restrict__ out_bf, const float* __restrict__ part,
    const float* __restrict__ gamma, const float* __restrict__ beta,
    const float* __restrict__ x_hsi, float* __restrict__ out)
{
    __shared__ float sstat[64];
    if (threadIdx.x < 32) {
        float S = part[threadIdx.x * 2];
        float Q = part[threadIdx.x * 2 + 1];
        const float inv_n = 1.0f / 131072.0f;
        float mean = S * inv_n;
        float var  = Q * inv_n - mean * mean;
        sstat[threadIdx.x * 2]     = mean;
        sstat[threadIdx.x * 2 + 1] = rsqrtf(var + 1e-5f);
    }
    __syncthreads();
    const int idx4 = blockIdx.x * 256 + threadIdx.x;
    const int flat = idx4 * 4;
    const int c = (flat >> 12) & 127;
    const int b = flat >> 19;
    const int g = c >> 5;
    const float mean = sstat[(b * 4 + g) * 2];
    const float inv  = sstat[(b * 4 + g) * 2 + 1];
    const float ga = gamma[c], be = beta[c];
    ushort4 u = *(const ushort4*)&out_bf[flat];
    float4 r = *(const float4*)&x_hsi[flat];
    float vv[4] = {bf2f(u.x), bf2f(u.y), bf2f(u.z), bf2f(u.w)};
    float rr[4] = {r.x, r.y, r.z, r.w};
    float o[4];
    #pragma unroll
    for (int qq = 0; qq < 4; ++qq) {
        float xn = (vv[qq] - mean) * inv;
        float gv = xn * ga + be;
        o[qq] = silu_fast(gv) + rr[qq];
    }
    *(float4*)&out[flat] = make_float4(o[0], o[1], o[2], o[3]);
}

// ---------------------------------------------------------------------------
extern "C" void kernel_launch(void* const* d_in, const int* in_sizes, int n_in,
                              void* d_out, int out_size, void* d_ws, size_t ws_size,
                              hipStream_t stream)
{
    const float* x_hsi  = (const float*)d_in[0];
    const float* W_in   = (const float*)d_in[1];
    const float* conv_w = (const float*)d_in[2];
    const float* conv_b = (const float*)d_in[3];
    const float* W_x    = (const float*)d_in[4];
    const float* W_dt   = (const float*)d_in[5];
    const float* b_dt   = (const float*)d_in[6];
    const float* A_log  = (const float*)d_in[7];
    const float* Dv     = (const float*)d_in[8];
    const float* W_out  = (const float*)d_in[9];
    const float* gnw    = (const float*)d_in[10];
    const float* gnb    = (const float*)d_in[11];

    float* ws = (float*)d_ws;
    unsigned short* xhbf = (unsigned short*)(ws + 0);          // 8,388,608 us
    unsigned short* zbf  = (unsigned short*)(ws + 4194304);    // 8,388,608 us
    float* xdbl   = ws + 8388608;      // 327,680 f
    float* hx     = ws + 8716288;      // 4,194,304 f  (8*128*4096) hend -> hin
    float* dtsg   = ws + 12910592;     // 262,144 f
    unsigned short* xcbf   = (unsigned short*)(ws + 13172736); // 8,388,608 us
    unsigned short* out_bf = (unsigned short*)(ws + 17367040); // 4,194,304 us
    float* part   = ws + 19464192;     // 64 f
    unsigned short* wtin  = (unsigned short*)(ws + 19464256);  // 65,536 us
    unsigned short* wtout = (unsigned short*)(ws + 19497024);  // 32,768 us
    unsigned short* wxt   = (unsigned short*)(ws + 19513408);  // 12,288 us
    __half* dtvh  = (__half*)(ws + 19519552);                  // 8,388,608 h
    float* outp   = (float*)d_out;

    k0_setup<<<26, 256, 0, stream>>>(W_in, W_out, W_x, wtin, wtout, wxt, part);
    k1_gemm_in<<<dim3(256, 2), 512, 0, stream>>>(x_hsi, wtin, xhbf, zbf);
    k46_conv_xdbl<<<dim3(NCH, BATCH), 256, 0, stream>>>(
        xhbf, conv_w, conv_b, wxt, xdbl, xcbf);
    k6_scan1<<<dim3(NCH, BATCH), 256, 0, stream>>>(
        xcbf, xdbl, W_dt, b_dt, A_log, hx, dtsg, dtvh);
    k7_combine<<<128, 256, 0, stream>>>(dtsg, A_log, hx);
    k89_scan2_gemm_out<<<dim3(NCH, BATCH), 256, 0, stream>>>(
        xcbf, xdbl, dtvh, A_log, Dv, hx, zbf, wtout, out_bf, part);
    k10c_apply<<<4096, 256, 0, stream>>>(out_bf, part, gnw, gnb, x_hsi, outp);
}

// Round 7
// 192.109 us; speedup vs baseline: 1.7979x; 1.7979x over previous
//
#include <hip/hip_runtime.h>
#include <hip/hip_bf16.h>
#include <hip/hip_fp16.h>
#include <math.h>

// Problem constants
#define BATCH   8
#define LSEQ    4096      // 64*64
#define CMODEL  128
#define DIN     256
#define NSTATE  16
#define RRANK   8
#define NCH     128       // chunks per sequence
#define TCH     32        // timesteps per chunk (NCH*TCH == LSEQ)

typedef __attribute__((ext_vector_type(8))) short short8;
typedef __attribute__((ext_vector_type(4))) float f32x4;
typedef __attribute__((ext_vector_type(2))) float f32x2;

__device__ __forceinline__ float sigmoid_fast(float x) {
    return __builtin_amdgcn_rcpf(1.0f + __expf(-x));
}
__device__ __forceinline__ float silu_fast(float x) { return x * sigmoid_fast(x); }
__device__ __forceinline__ float softplus_fast(float x) {
    return fmaxf(x, 0.0f) + __logf(1.0f + __expf(-fabsf(x)));
}
__device__ __forceinline__ float bf2f(unsigned short u) {
    return __uint_as_float(((unsigned)u) << 16);
}
// packed fp32x2 -> bf16x2 (v_cvt_pk_bf16_f32); a -> low, b -> high
__device__ __forceinline__ unsigned pk2bf(float a, float b) {
    __hip_bfloat162 t = __float22bfloat162_rn(make_float2(a, b));
    unsigned r;
    __builtin_memcpy(&r, &t, 4);
    return r;
}
__device__ __forceinline__ unsigned short f2bf1(float v) {   // 1-op scalar cvt
    return (unsigned short)pk2bf(v, v);
}

// dA2[j] = {exp(dtv*A[2j]), exp(dtv*A[2j+1])}; fast path via packed mul chain.
__device__ __forceinline__ void dA_powers2(float dtv, const float* A, bool fast,
                                           f32x2* dA2)
{
    if (fast) {
        float e1 = __expf(dtv * A[0]);
        float e2 = e1 * e1;
        dA2[0] = (f32x2){e1, e2};
        f32x2 e2s = (f32x2){e2, e2};
        #pragma unroll
        for (int j = 1; j < 8; ++j) dA2[j] = dA2[j-1] * e2s;
    } else {
        #pragma unroll
        for (int j = 0; j < 8; ++j)
            dA2[j] = (f32x2){__expf(dtv * A[2*j]), __expf(dtv * A[2*j+1])};
    }
}

#define LSTR 72   // LDS row stride (bf16 units): 64 data + 8 pad; 2-way max = free
#define YSTR 264  // full-width y/xc tile stride (256 data + 8 pad)

// ---------------------------------------------------------------------------
// K0: weight transposes (tiny) + W_x^T + part zero. grid 26, block 256
// ---------------------------------------------------------------------------
__device__ __forceinline__ void tr64_bf(const float* __restrict__ src, int lds,
                                        int r0, int c0,
                                        unsigned short* __restrict__ dst, int ldd)
{
    __shared__ float ts[64][65];
    const int tid = threadIdx.x;
    #pragma unroll
    for (int it = 0; it < 4; ++it) {
        int slot = tid + it * 256;
        int i = slot >> 4, j4 = slot & 15;
        float4 v = *(const float4*)&src[(size_t)(r0 + i) * lds + c0 + j4 * 4];
        ts[i][j4*4+0] = v.x; ts[i][j4*4+1] = v.y;
        ts[i][j4*4+2] = v.z; ts[i][j4*4+3] = v.w;
    }
    __syncthreads();
    #pragma unroll
    for (int it = 0; it < 4; ++it) {
        int slot = tid + it * 256;
        int row = slot >> 4, c4 = slot & 15;
        unsigned p0 = pk2bf(ts[c4*4+0][row], ts[c4*4+1][row]);
        unsigned p1 = pk2bf(ts[c4*4+2][row], ts[c4*4+3][row]);
        unsigned long long u = (unsigned long long)p0 | ((unsigned long long)p1 << 32);
        *(unsigned long long*)&dst[(size_t)(c0 + row) * ldd + r0 + c4 * 4] = u;
    }
}

__global__ __launch_bounds__(256) void k0_setup(
    const float* __restrict__ W_in, const float* __restrict__ W_out,
    const float* __restrict__ W_x,
    unsigned short* __restrict__ wtin, unsigned short* __restrict__ wtout,
    unsigned short* __restrict__ wxt, float* __restrict__ part)
{
    const int bid = blockIdx.x;
    if (bid < 16) {
        int ct = bid >> 3, jt = bid & 7;
        tr64_bf(W_in, 512, ct * 64, jt * 64, wtin, 128);
    } else if (bid < 24) {
        int t3 = bid - 16;
        int kt = t3 >> 1, ct = t3 & 1;
        tr64_bf(W_out, 128, kt * 64, ct * 64, wtout, 256);
    } else if (bid == 24) {
        // W_x [256 k][40 j] -> wxt [48 j][256 k] bf16 (rows 40..47 zero)
        for (int idx = threadIdx.x; idx < 48 * 256; idx += 256) {
            int j = idx >> 8, k = idx & 255;
            float v = (j < 40) ? W_x[k * 40 + j] : 0.0f;
            wxt[(size_t)j * 256 + k] = f2bf1(v);
        }
    } else {
        if (threadIdx.x < 64) part[threadIdx.x] = 0.0f;
    }
}

// ---------------------------------------------------------------------------
// K1 (MFMA bf16): xz = x @ W_in. 128(l) x 256(j) tile, 8 waves, K=128 in
// chunks of 64. Staged Bbf (LDS) for wtin -- measured faster than
// direct-global B-frags (R3 vs R4: ~13 us). grid (256, 2), block 512
// ---------------------------------------------------------------------------
__global__ __launch_bounds__(512) void k1_gemm_in(
    const float* __restrict__ x_hsi, const unsigned short* __restrict__ wtin,
    unsigned short* __restrict__ xhbf, unsigned short* __restrict__ zbf)
{
    __shared__ __align__(16) unsigned short Abf[128 * LSTR];   // rows = l
    __shared__ __align__(16) unsigned short Bbf[256 * LSTR];   // rows = j
    const int tid = threadIdx.x;
    const int R0  = blockIdx.x * 128;         // global row (b*L + l)
    const int b   = R0 >> 12;
    const int l0  = R0 & 4095;
    const int jbase = blockIdx.y * 256;

    const int w    = tid >> 6;                // 0..7
    const int lane = tid & 63;
    const int lm   = lane & 15;
    const int q    = lane >> 4;
    const int mbase = (w & 1) * 64;           // l-quadrant
    const int nbase = (w >> 1) * 64;          // j-quadrant (0..192)

    f32x4 acc[4][4];
    #pragma unroll
    for (int i = 0; i < 4; ++i)
        #pragma unroll
        for (int j = 0; j < 4; ++j) acc[i][j] = (f32x4){0.f, 0.f, 0.f, 0.f};

    const int cq = tid & 15;                  // c-quad within chunk (16*4=64)
    const int lq = tid >> 4;                  // l-quad (32*4=128)

    for (int kc = 0; kc < 128; kc += 64) {
        __syncthreads();
        // stage A: x[c][l] -> Abf[l][c_local] (transpose + packed cvt)
        {
            float v[4][4];
            #pragma unroll
            for (int t = 0; t < 4; ++t) {
                float4 f = *(const float4*)&x_hsi[((b * 128 + kc + cq * 4 + t) << 12) + l0 + lq * 4];
                v[t][0] = f.x; v[t][1] = f.y; v[t][2] = f.z; v[t][3] = f.w;
            }
            #pragma unroll
            for (int i = 0; i < 4; ++i) {
                unsigned p0 = pk2bf(v[0][i], v[1][i]);
                unsigned p1 = pk2bf(v[2][i], v[3][i]);
                unsigned long long u = (unsigned long long)p0 | ((unsigned long long)p1 << 32);
                *(unsigned long long*)&Abf[(lq * 4 + i) * LSTR + cq * 4] = u;
            }
        }
        // stage B: direct bf16 copy from wtin (256 rows x 8 segs)
        #pragma unroll
        for (int it = 0; it < 4; ++it) {
            int slot = tid + it * 512;
            int r = slot >> 3, seg = slot & 7;
            short8 vb = *(const short8*)&wtin[(size_t)(jbase + r) * 128 + kc + seg * 8];
            *(short8*)&Bbf[r * LSTR + seg * 8] = vb;
        }
        __syncthreads();
        #pragma unroll
        for (int kt = 0; kt < 2; ++kt) {
            short8 af[4], bfr[4];
            #pragma unroll
            for (int mt = 0; mt < 4; ++mt)
                af[mt] = *(const short8*)&Abf[(mbase + mt * 16 + lm) * LSTR + kt * 32 + q * 8];
            #pragma unroll
            for (int nt = 0; nt < 4; ++nt)
                bfr[nt] = *(const short8*)&Bbf[(nbase + nt * 16 + lm) * LSTR + kt * 32 + q * 8];
            #pragma unroll
            for (int mt = 0; mt < 4; ++mt)
                #pragma unroll
                for (int nt = 0; nt < 4; ++nt)
                    acc[mt][nt] = __builtin_amdgcn_mfma_f32_16x16x32_bf16(
                        af[mt], bfr[nt], acc[mt][nt], 0, 0, 0);
        }
    }

    const bool is_xh = (jbase == 0);
    #pragma unroll
    for (int mt = 0; mt < 4; ++mt) {
        #pragma unroll
        for (int r = 0; r < 4; ++r) {
            int row = R0 + mbase + mt * 16 + q * 4 + r;
            #pragma unroll
            for (int nt = 0; nt < 4; ++nt) {
                int col = nbase + nt * 16 + lm;     // 0..255
                float val = acc[mt][nt][r];
                if (is_xh) xhbf[row * 256 + col] = f2bf1(val);
                else       zbf[row * 256 + col]  = f2bf1(silu_fast(val));
            }
        }
    }
}

// ---------------------------------------------------------------------------
// K46 (fused): conv_silu(xh) -> xcb (LDS bf16 + global xcbf)
//              -> x_dbl via MFMA (A = xcb LDS, B = wxt global direct)
//              -> scan pass 1 (xdl fp32 in LDS). As measured in R4.
// One block = one chunk (32 t x 256 d). grid (NCH, BATCH), block 256.
// ---------------------------------------------------------------------------
__global__ __launch_bounds__(256) void k46_conv_gemm_scan1(
    const unsigned short* __restrict__ xhbf, const float* __restrict__ conv_w,
    const float* __restrict__ conv_b, const unsigned short* __restrict__ wxt,
    const float* __restrict__ W_dt, const float* __restrict__ b_dt,
    const float* __restrict__ A_log,
    float* __restrict__ xdbl, unsigned short* __restrict__ xcbf,
    float* __restrict__ hend, float* __restrict__ dtsg)
{
    __shared__ float cw0[256], cw1[256], cbs[256];
    __shared__ __align__(16) unsigned short xcb[TCH][YSTR]; // conv tile bf16
    __shared__ __align__(16) float xdl[TCH * 40];           // x_dbl fp32
    const int tid = threadIdx.x;
    const int chunk = blockIdx.x;
    const int b = blockIdx.y;
    const int R0 = b * LSEQ + chunk * TCH;

    cw0[tid] = conv_w[2 * tid];
    cw1[tid] = conv_w[2 * tid + 1];
    cbs[tid] = conv_b[tid];

    // scan constants (issued early; used after the GEMM phase)
    const int d = tid;
    float A[16];
    #pragma unroll
    for (int qq = 0; qq < 4; ++qq) {
        float4 al = *(const float4*)&A_log[d * 16 + qq * 4];
        A[qq*4+0] = -__expf(al.x); A[qq*4+1] = -__expf(al.y);
        A[qq*4+2] = -__expf(al.z); A[qq*4+3] = -__expf(al.w);
    }
    bool fast = true;
    #pragma unroll
    for (int n = 1; n < 16; ++n)
        fast = fast && (fabsf(A[n] - (n + 1) * A[0]) <= 1e-4f * fabsf(A[n]) + 1e-7f);
    float wdt[8];
    #pragma unroll
    for (int r = 0; r < 8; ++r) wdt[r] = W_dt[r * 256 + d];
    const float bdt = b_dt[d];

    __syncthreads();   // cw ready

    // ---- conv + silu: whole 32 x 256 tile -> xcb (bf16) + xcbf (global) ----
    #pragma unroll
    for (int it = 0; it < 8; ++it) {
        int idx = tid + it * 256;            // 32 rows x 64 quads
        int r = idx >> 6, qq = idx & 63;
        int row = R0 + r;
        int dd = qq * 4;
        ushort4 cu = *(const ushort4*)&xhbf[(size_t)row * 256 + dd];
        float cur[4] = {bf2f(cu.x), bf2f(cu.y), bf2f(cu.z), bf2f(cu.w)};
        float pv[4] = {0.f, 0.f, 0.f, 0.f};
        if ((row & 4095) != 0) {
            ushort4 pu = *(const ushort4*)&xhbf[(size_t)(row - 1) * 256 + dd];
            pv[0] = bf2f(pu.x); pv[1] = bf2f(pu.y);
            pv[2] = bf2f(pu.z); pv[3] = bf2f(pu.w);
        }
        float o[4];
        #pragma unroll
        for (int e = 0; e < 4; ++e)
            o[e] = silu_fast(pv[e] * cw0[dd+e] + cur[e] * cw1[dd+e] + cbs[dd+e]);
        unsigned p0 = pk2bf(o[0], o[1]), p1 = pk2bf(o[2], o[3]);
        unsigned long long u = (unsigned long long)p0 | ((unsigned long long)p1 << 32);
        *(unsigned long long*)&xcb[r][dd] = u;
        *(unsigned long long*)&xcbf[(size_t)row * 256 + dd] = u;
    }
    __syncthreads();

    // ---- x_dbl = xcb @ W_x via MFMA (out 32 x 40, K = 256) ----
    // tiles: wave0: m0 n{0,1}; wave1: m1 n{0,1}; wave2: m0 n{2}; wave3: m1 n{2}
    const int w    = tid >> 6;
    const int lane = tid & 63;
    const int lm   = lane & 15;
    const int q    = lane >> 4;
    {
        const int mt  = w & 1;
        const int nlo = (w < 2) ? 0 : 2;
        const int nn  = (w < 2) ? 2 : 1;
        f32x4 macc[2];
        macc[0] = (f32x4){0.f,0.f,0.f,0.f};
        macc[1] = (f32x4){0.f,0.f,0.f,0.f};
        for (int kc = 0; kc < 256; kc += 32) {
            short8 af = *(const short8*)&xcb[mt * 16 + lm][kc + q * 8];
            #pragma unroll
            for (int t = 0; t < 2; ++t) {
                if (t < nn) {
                    short8 bfr = *(const short8*)&wxt[(size_t)((nlo + t) * 16 + lm) * 256 + kc + q * 8];
                    macc[t] = __builtin_amdgcn_mfma_f32_16x16x32_bf16(
                        af, bfr, macc[t], 0, 0, 0);
                }
            }
        }
        #pragma unroll
        for (int t = 0; t < 2; ++t) {
            if (t < nn) {
                #pragma unroll
                for (int r = 0; r < 4; ++r) {
                    int row = mt * 16 + q * 4 + r;
                    int col = (nlo + t) * 16 + lm;
                    if (col < 40) {
                        float v = macc[t][r];
                        xdl[row * 40 + col] = v;
                        xdbl[(size_t)(R0 + row) * 40 + col] = v;
                    }
                }
            }
        }
    }
    __syncthreads();

    // ---- scan pass 1 (h_in = 0), all data resident in LDS ----
    f32x2 h2[8];
    #pragma unroll
    for (int j = 0; j < 8; ++j) h2[j] = (f32x2){0.f, 0.f};
    float dtsum = 0.f;

    #pragma unroll 2
    for (int tt = 0; tt < TCH; ++tt) {
        float xcv = bf2f(xcb[tt][d]);

        float dl[8];
        *(float4*)&dl[0] = *(const float4*)&xdl[tt * 40 + 0];
        *(float4*)&dl[4] = *(const float4*)&xdl[tt * 40 + 4];
        float dtr = bdt;
        #pragma unroll
        for (int r = 0; r < 8; ++r) dtr = fmaf(dl[r], wdt[r], dtr);
        float dtv = softplus_fast(dtr);
        dtsum += dtv;
        float dtx = dtv * xcv;

        float Bv[16];
        *(float4*)&Bv[0]  = *(const float4*)&xdl[tt * 40 + 8];
        *(float4*)&Bv[4]  = *(const float4*)&xdl[tt * 40 + 12];
        *(float4*)&Bv[8]  = *(const float4*)&xdl[tt * 40 + 16];
        *(float4*)&Bv[12] = *(const float4*)&xdl[tt * 40 + 20];

        f32x2 dA2[8];
        dA_powers2(dtv, A, fast, dA2);
        f32x2 dtx2 = (f32x2){dtx, dtx};
        #pragma unroll
        for (int j = 0; j < 8; ++j) {
            f32x2 Bt2 = (f32x2){Bv[2*j], Bv[2*j+1]};
            h2[j] = dA2[j] * h2[j] + dtx2 * Bt2;
        }
    }

    const float* hf = (const float*)h2;
    const int base = ((b * NCH + chunk) * 256 + d) * 16;
    #pragma unroll
    for (int qq = 0; qq < 4; ++qq)
        *(float4*)&hend[base + qq * 4] = make_float4(hf[qq*4], hf[qq*4+1], hf[qq*4+2], hf[qq*4+3]);
    dtsg[(b * NCH + chunk) * 256 + d] = dtsum;
}

// ---------------------------------------------------------------------------
// Scan pass 2: sequential combine with P(c) = exp(dtsum(c)*A[n]) on the fly;
// hx: hend -> hin in-place. 8-deep prefetch, NCH/8 = 16 groups.
// grid 128, block 256
// ---------------------------------------------------------------------------
__global__ __launch_bounds__(256) void k7_combine(
    const float* __restrict__ dtsg, const float* __restrict__ A_log,
    float* __restrict__ hx)
{
    const int idx = blockIdx.x * 256 + threadIdx.x;   // b*4096 + d*16 + n
    const int b = idx >> 12;
    const int rem = idx & 4095;
    const int d = rem >> 4, n = rem & 15;
    const float An = -__expf(A_log[d * 16 + n]);
    const int base = b * NCH * 4096 + rem;            // hx index, +4096/chunk
    const int sbase = b * NCH * 256 + d;              // dtsg index, +256/chunk
    float h = 0.f;
    float Sb[8], Eb[8];
    #pragma unroll
    for (int j = 0; j < 8; ++j) {
        Sb[j] = dtsg[sbase + j * 256];
        Eb[j] = hx[base + j * 4096];
    }
    for (int g = 0; g < NCH / 8; ++g) {
        const int o  = base + g * 32768;
        const int so = sbase + g * 2048;
        float Sn[8] = {0,0,0,0,0,0,0,0}, En[8] = {0,0,0,0,0,0,0,0};
        if (g < NCH / 8 - 1) {
            #pragma unroll
            for (int j = 0; j < 8; ++j) {
                Sn[j] = dtsg[so + 2048 + j * 256];
                En[j] = hx[o + 32768 + j * 4096];
            }
        }
        #pragma unroll
        for (int j = 0; j < 8; ++j) {
            hx[o + j * 4096] = h;
            float P = __expf(Sb[j] * An);
            h = fmaf(P, h, Eb[j]);
        }
        #pragma unroll
        for (int j = 0; j < 8; ++j) { Sb[j] = Sn[j]; Eb[j] = En[j]; }
    }
}

// ---------------------------------------------------------------------------
// K89 (fused): scan pass 3 (xdbl via wave-uniform scalar loads, no LDS
// staging) -> y*silu(z) into Ybf LDS tile (bf16) -> MFMA out-GEMM with
// A-frags direct from global wtout + fused GN partials. As measured in R5
// (42.4 us, VGPR 44). One block = one chunk (32 t x 256 d).
// grid (NCH, BATCH), block 256. LDS ~17 KB (Ybf only).
// ---------------------------------------------------------------------------
__global__ __launch_bounds__(256) void k89_scan2_gemm_out(
    const unsigned short* __restrict__ xcbf, const float* __restrict__ xdbl,
    const float* __restrict__ W_dt, const float* __restrict__ b_dt,
    const float* __restrict__ A_log, const float* __restrict__ Dvec,
    const float* __restrict__ hin, const unsigned short* __restrict__ zbf,
    const unsigned short* __restrict__ wtout,
    unsigned short* __restrict__ out_bf, float* __restrict__ part)
{
    __shared__ __align__(16) unsigned short Ybf[TCH][YSTR];    // y tile (rows=l)
    __shared__ float pred[8];
    const int tid = threadIdx.x;
    const int chunk = blockIdx.x;
    const int b = blockIdx.y;
    const int t0 = b * LSEQ + chunk * TCH;

    if (tid < 8) pred[tid] = 0.0f;

    const int d = tid;
    float A[16];
    #pragma unroll
    for (int qq = 0; qq < 4; ++qq) {
        float4 al = *(const float4*)&A_log[d * 16 + qq * 4];
        A[qq*4+0] = -__expf(al.x); A[qq*4+1] = -__expf(al.y);
        A[qq*4+2] = -__expf(al.z); A[qq*4+3] = -__expf(al.w);
    }
    bool fast = true;
    #pragma unroll
    for (int n = 1; n < 16; ++n)
        fast = fast && (fabsf(A[n] - (n + 1) * A[0]) <= 1e-4f * fabsf(A[n]) + 1e-7f);
    float wdt[8];
    #pragma unroll
    for (int r = 0; r < 8; ++r) wdt[r] = W_dt[r * 256 + d];
    const float bdt = b_dt[d];
    const float Dd = Dvec[d];

    f32x2 h2[8];
    {
        const int hbase = ((b * NCH + chunk) * 256 + d) * 16;
        float hf[16];
        #pragma unroll
        for (int qq = 0; qq < 4; ++qq) {
            float4 hv = *(const float4*)&hin[hbase + qq * 4];
            hf[qq*4+0] = hv.x; hf[qq*4+1] = hv.y; hf[qq*4+2] = hv.z; hf[qq*4+3] = hv.w;
        }
        #pragma unroll
        for (int j = 0; j < 8; ++j) h2[j] = (f32x2){hf[2*j], hf[2*j+1]};
    }

    // ---- scan pass 3: y -> Ybf (bf16, already gated by silu(z)) ----
    #pragma unroll 2
    for (int tt = 0; tt < TCH; ++tt) {
        const int row = t0 + tt;
        const size_t gi = (size_t)row * 256 + d;
        float xcv = bf2f(xcbf[gi]);

        // wave-uniform rows of xdbl -> scalar loads
        const float* xr = &xdbl[(size_t)row * 40];
        float dl[8], Bv[16], Cv[16];
        *(float4*)&dl[0] = *(const float4*)&xr[0];
        *(float4*)&dl[4] = *(const float4*)&xr[4];
        *(float4*)&Bv[0]  = *(const float4*)&xr[8];
        *(float4*)&Bv[4]  = *(const float4*)&xr[12];
        *(float4*)&Bv[8]  = *(const float4*)&xr[16];
        *(float4*)&Bv[12] = *(const float4*)&xr[20];
        *(float4*)&Cv[0]  = *(const float4*)&xr[24];
        *(float4*)&Cv[4]  = *(const float4*)&xr[28];
        *(float4*)&Cv[8]  = *(const float4*)&xr[32];
        *(float4*)&Cv[12] = *(const float4*)&xr[36];

        float dtr = bdt;
        #pragma unroll
        for (int r = 0; r < 8; ++r) dtr = fmaf(dl[r], wdt[r], dtr);
        float dtv = softplus_fast(dtr);
        float dtx = dtv * xcv;

        f32x2 dA2[8];
        dA_powers2(dtv, A, fast, dA2);
        f32x2 dtx2 = (f32x2){dtx, dtx};
        f32x2 yv2 = (f32x2){0.f, 0.f};
        #pragma unroll
        for (int j = 0; j < 8; ++j) {
            f32x2 Bt2 = (f32x2){Bv[2*j], Bv[2*j+1]};
            f32x2 Ct2 = (f32x2){Cv[2*j], Cv[2*j+1]};
            h2[j] = dA2[j] * h2[j] + dtx2 * Bt2;
            yv2 = yv2 + h2[j] * Ct2;
        }
        float yv = yv2.x + yv2.y;
        yv = fmaf(Dd, xcv, yv);
        Ybf[tt][d] = f2bf1(yv * bf2f(zbf[gi]));
    }
    __syncthreads();

    // ---- MFMA out-GEMM: out[c][l] = sum_k wtout[c][k] * y[l][k] ----
    // A-frags direct from global wtout (L2-hot); B-frags from Ybf LDS.
    const int w    = tid >> 6;
    const int lane = tid & 63;
    const int lm   = lane & 15;
    const int q    = lane >> 4;
    const int mbase = (w & 1) * 64;           // c-half
    const int nbase = (w >> 1) * 16;          // l-half (of 32)

    f32x4 acc[4];
    #pragma unroll
    for (int i = 0; i < 4; ++i) acc[i] = (f32x4){0.f, 0.f, 0.f, 0.f};

    for (int ks = 0; ks < 256; ks += 32) {
        short8 bfr = *(const short8*)&Ybf[nbase + lm][ks + q * 8];
        #pragma unroll
        for (int mt = 0; mt < 4; ++mt) {
            short8 af = *(const short8*)&wtout[(size_t)(mbase + mt * 16 + lm) * 256 + ks + q * 8];
            acc[mt] = __builtin_amdgcn_mfma_f32_16x16x32_bf16(
                af, bfr, acc[mt], 0, 0, 0);
        }
    }

    const int l0 = chunk * TCH;
    #pragma unroll
    for (int mt = 0; mt < 4; ++mt) {
        #pragma unroll
        for (int r = 0; r < 4; ++r) {
            int c = mbase + mt * 16 + q * 4 + r;
            long obase = (long)(b * 128 + c) * 4096 + l0;
            out_bf[obase + nbase + lm] = f2bf1(acc[mt][r]);
        }
    }

    // fused GroupNorm partial sums (fp32 from accumulators)
    float s0 = 0.f, q0 = 0.f, s1 = 0.f, q1 = 0.f;
    #pragma unroll
    for (int mt = 0; mt < 4; ++mt)
        #pragma unroll
        for (int r = 0; r < 4; ++r) {
            float v = acc[mt][r];
            if (mt < 2) { s0 += v; q0 += v * v; }
            else        { s1 += v; q1 += v * v; }
        }
    #pragma unroll
    for (int off = 32; off > 0; off >>= 1) {
        s0 += __shfl_down(s0, off, 64);
        q0 += __shfl_down(q0, off, 64);
        s1 += __shfl_down(s1, off, 64);
        q1 += __shfl_down(q1, off, 64);
    }
    if (lane == 0) {
        int g0 = mbase >> 5;                  // 0 or 2
        atomicAdd(&pred[g0 * 2],           s0);
        atomicAdd(&pred[g0 * 2 + 1],       q0);
        atomicAdd(&pred[(g0 + 1) * 2],     s1);
        atomicAdd(&pred[(g0 + 1) * 2 + 1], q1);
    }
    __syncthreads();
    if (tid < 8) atomicAdd(&part[b * 8 + tid], pred[tid]);
}

// K10c: apply GN + silu + residual (stat from part; out_bf bf16).
// grid 4096, block 256
__global__ __launch_bounds__(256) void k10c_apply(
    const unsigned short* __restrict__ out_bf, const float* __restrict__ part,
    const float* __restrict__ gamma, const float* __restrict__ beta,
    const float* __restrict__ x_hsi, float* __restrict__ out)
{
    __shared__ float sstat[64];
    if (threadIdx.x < 32) {
        float S = part[threadIdx.x * 2];
        float Q = part[threadIdx.x * 2 + 1];
        const float inv_n = 1.0f / 131072.0f;
        float mean = S * inv_n;
        float var  = Q * inv_n - mean * mean;
        sstat[threadIdx.x * 2]     = mean;
        sstat[threadIdx.x * 2 + 1] = rsqrtf(var + 1e-5f);
    }
    __syncthreads();
    const int idx4 = blockIdx.x * 256 + threadIdx.x;
    const int flat = idx4 * 4;
    const int c = (flat >> 12) & 127;
    const int b = flat >> 19;
    const int g = c >> 5;
    const float mean = sstat[(b * 4 + g) * 2];
    const float inv  = sstat[(b * 4 + g) * 2 + 1];
    const float ga = gamma[c], be = beta[c];
    ushort4 u = *(const ushort4*)&out_bf[flat];
    float4 r = *(const float4*)&x_hsi[flat];
    float vv[4] = {bf2f(u.x), bf2f(u.y), bf2f(u.z), bf2f(u.w)};
    float rr[4] = {r.x, r.y, r.z, r.w};
    float o[4];
    #pragma unroll
    for (int qq = 0; qq < 4; ++qq) {
        float xn = (vv[qq] - mean) * inv;
        float gv = xn * ga + be;
        o[qq] = silu_fast(gv) + rr[qq];
    }
    *(float4*)&out[flat] = make_float4(o[0], o[1], o[2], o[3]);
}

// ---------------------------------------------------------------------------
extern "C" void kernel_launch(void* const* d_in, const int* in_sizes, int n_in,
                              void* d_out, int out_size, void* d_ws, size_t ws_size,
                              hipStream_t stream)
{
    const float* x_hsi  = (const float*)d_in[0];
    const float* W_in   = (const float*)d_in[1];
    const float* conv_w = (const float*)d_in[2];
    const float* conv_b = (const float*)d_in[3];
    const float* W_x    = (const float*)d_in[4];
    const float* W_dt   = (const float*)d_in[5];
    const float* b_dt   = (const float*)d_in[6];
    const float* A_log  = (const float*)d_in[7];
    const float* Dv     = (const float*)d_in[8];
    const float* W_out  = (const float*)d_in[9];
    const float* gnw    = (const float*)d_in[10];
    const float* gnb    = (const float*)d_in[11];

    float* ws = (float*)d_ws;
    unsigned short* xhbf = (unsigned short*)(ws + 0);          // 8,388,608 us
    unsigned short* zbf  = (unsigned short*)(ws + 4194304);    // 8,388,608 us
    float* xdbl   = ws + 8388608;      // 327,680 f
    float* hx     = ws + 8716288;      // 4,194,304 f  (8*128*4096) hend -> hin
    float* dtsg   = ws + 12910592;     // 262,144 f
    unsigned short* xcbf   = (unsigned short*)(ws + 13172736); // 8,388,608 us
    unsigned short* out_bf = (unsigned short*)(ws + 17367040); // 4,194,304 us
    float* part   = ws + 19464192;     // 64 f
    unsigned short* wtin  = (unsigned short*)(ws + 19464256);  // 65,536 us
    unsigned short* wtout = (unsigned short*)(ws + 19497024);  // 32,768 us
    unsigned short* wxt   = (unsigned short*)(ws + 19513408);  // 12,288 us
    float* outp   = (float*)d_out;

    k0_setup<<<26, 256, 0, stream>>>(W_in, W_out, W_x, wtin, wtout, wxt, part);
    k1_gemm_in<<<dim3(256, 2), 512, 0, stream>>>(x_hsi, wtin, xhbf, zbf);
    k46_conv_gemm_scan1<<<dim3(NCH, BATCH), 256, 0, stream>>>(
        xhbf, conv_w, conv_b, wxt, W_dt, b_dt, A_log, xdbl, xcbf, hx, dtsg);
    k7_combine<<<128, 256, 0, stream>>>(dtsg, A_log, hx);
    k89_scan2_gemm_out<<<dim3(NCH, BATCH), 256, 0, stream>>>(
        xcbf, xdbl, W_dt, b_dt, A_log, Dv, hx, zbf, wtout, out_bf, part);
    k10c_apply<<<4096, 256, 0, stream>>>(out_bf, part, gnw, gnb, x_hsi, outp);
}

// Round 8
// 189.988 us; speedup vs baseline: 1.8180x; 1.0112x over previous
//
#include <hip/hip_runtime.h>
#include <hip/hip_bf16.h>
#include <hip/hip_fp16.h>
#include <math.h>

// Problem constants
#define BATCH   8
#define LSEQ    4096      // 64*64
#define CMODEL  128
#define DIN     256
#define NSTATE  16
#define RRANK   8
#define NCH     128       // chunks per sequence
#define TCH     32        // timesteps per chunk (NCH*TCH == LSEQ)

typedef __attribute__((ext_vector_type(8))) short short8;
typedef __attribute__((ext_vector_type(4))) float f32x4;
typedef __attribute__((ext_vector_type(2))) float f32x2;

__device__ __forceinline__ float sigmoid_fast(float x) {
    return __builtin_amdgcn_rcpf(1.0f + __expf(-x));
}
__device__ __forceinline__ float silu_fast(float x) { return x * sigmoid_fast(x); }
__device__ __forceinline__ float softplus_fast(float x) {
    return fmaxf(x, 0.0f) + __logf(1.0f + __expf(-fabsf(x)));
}
__device__ __forceinline__ float bf2f(unsigned short u) {
    return __uint_as_float(((unsigned)u) << 16);
}
// packed fp32x2 -> bf16x2 (v_cvt_pk_bf16_f32); a -> low, b -> high
__device__ __forceinline__ unsigned pk2bf(float a, float b) {
    __hip_bfloat162 t = __float22bfloat162_rn(make_float2(a, b));
    unsigned r;
    __builtin_memcpy(&r, &t, 4);
    return r;
}
__device__ __forceinline__ unsigned short f2bf1(float v) {   // 1-op scalar cvt
    return (unsigned short)pk2bf(v, v);
}

// dA2[j] = {exp(dtv*A[2j]), exp(dtv*A[2j+1])}; fast path via packed mul chain.
__device__ __forceinline__ void dA_powers2(float dtv, const float* A, bool fast,
                                           f32x2* dA2)
{
    if (fast) {
        float e1 = __expf(dtv * A[0]);
        float e2 = e1 * e1;
        dA2[0] = (f32x2){e1, e2};
        f32x2 e2s = (f32x2){e2, e2};
        #pragma unroll
        for (int j = 1; j < 8; ++j) dA2[j] = dA2[j-1] * e2s;
    } else {
        #pragma unroll
        for (int j = 0; j < 8; ++j)
            dA2[j] = (f32x2){__expf(dtv * A[2*j]), __expf(dtv * A[2*j+1])};
    }
}

#define LSTR 72   // LDS row stride (bf16 units): 64 data + 8 pad; 2-way max = free
#define YSTR 264  // full-width y/xc tile stride (256 data + 8 pad)

// ---------------------------------------------------------------------------
// K0: weight transposes (tiny) + W_x^T + part zero. grid 26, block 256
// ---------------------------------------------------------------------------
__device__ __forceinline__ void tr64_bf(const float* __restrict__ src, int lds,
                                        int r0, int c0,
                                        unsigned short* __restrict__ dst, int ldd)
{
    __shared__ float ts[64][65];
    const int tid = threadIdx.x;
    #pragma unroll
    for (int it = 0; it < 4; ++it) {
        int slot = tid + it * 256;
        int i = slot >> 4, j4 = slot & 15;
        float4 v = *(const float4*)&src[(size_t)(r0 + i) * lds + c0 + j4 * 4];
        ts[i][j4*4+0] = v.x; ts[i][j4*4+1] = v.y;
        ts[i][j4*4+2] = v.z; ts[i][j4*4+3] = v.w;
    }
    __syncthreads();
    #pragma unroll
    for (int it = 0; it < 4; ++it) {
        int slot = tid + it * 256;
        int row = slot >> 4, c4 = slot & 15;
        unsigned p0 = pk2bf(ts[c4*4+0][row], ts[c4*4+1][row]);
        unsigned p1 = pk2bf(ts[c4*4+2][row], ts[c4*4+3][row]);
        unsigned long long u = (unsigned long long)p0 | ((unsigned long long)p1 << 32);
        *(unsigned long long*)&dst[(size_t)(c0 + row) * ldd + r0 + c4 * 4] = u;
    }
}

__global__ __launch_bounds__(256) void k0_setup(
    const float* __restrict__ W_in, const float* __restrict__ W_out,
    const float* __restrict__ W_x,
    unsigned short* __restrict__ wtin, unsigned short* __restrict__ wtout,
    unsigned short* __restrict__ wxt, float* __restrict__ part)
{
    const int bid = blockIdx.x;
    if (bid < 16) {
        int ct = bid >> 3, jt = bid & 7;
        tr64_bf(W_in, 512, ct * 64, jt * 64, wtin, 128);
    } else if (bid < 24) {
        int t3 = bid - 16;
        int kt = t3 >> 1, ct = t3 & 1;
        tr64_bf(W_out, 128, kt * 64, ct * 64, wtout, 256);
    } else if (bid == 24) {
        // W_x [256 k][40 j] -> wxt [48 j][256 k] bf16 (rows 40..47 zero)
        for (int idx = threadIdx.x; idx < 48 * 256; idx += 256) {
            int j = idx >> 8, k = idx & 255;
            float v = (j < 40) ? W_x[k * 40 + j] : 0.0f;
            wxt[(size_t)j * 256 + k] = f2bf1(v);
        }
    } else {
        if (threadIdx.x < 64) part[threadIdx.x] = 0.0f;
    }
}

// ---------------------------------------------------------------------------
// K1 (MFMA bf16): xz = x @ W_in. 128(l) x 256(j) tile, 8 waves, K=128 in
// chunks of 64. Staged Bbf (LDS) for wtin (measured best, R3 vs R4).
// grid (256, 2), block 512
// ---------------------------------------------------------------------------
__global__ __launch_bounds__(512) void k1_gemm_in(
    const float* __restrict__ x_hsi, const unsigned short* __restrict__ wtin,
    unsigned short* __restrict__ xhbf, unsigned short* __restrict__ zbf)
{
    __shared__ __align__(16) unsigned short Abf[128 * LSTR];   // rows = l
    __shared__ __align__(16) unsigned short Bbf[256 * LSTR];   // rows = j
    const int tid = threadIdx.x;
    const int R0  = blockIdx.x * 128;         // global row (b*L + l)
    const int b   = R0 >> 12;
    const int l0  = R0 & 4095;
    const int jbase = blockIdx.y * 256;

    const int w    = tid >> 6;                // 0..7
    const int lane = tid & 63;
    const int lm   = lane & 15;
    const int q    = lane >> 4;
    const int mbase = (w & 1) * 64;           // l-quadrant
    const int nbase = (w >> 1) * 64;          // j-quadrant (0..192)

    f32x4 acc[4][4];
    #pragma unroll
    for (int i = 0; i < 4; ++i)
        #pragma unroll
        for (int j = 0; j < 4; ++j) acc[i][j] = (f32x4){0.f, 0.f, 0.f, 0.f};

    const int cq = tid & 15;                  // c-quad within chunk (16*4=64)
    const int lq = tid >> 4;                  // l-quad (32*4=128)

    for (int kc = 0; kc < 128; kc += 64) {
        __syncthreads();
        // stage A: x[c][l] -> Abf[l][c_local] (transpose + packed cvt)
        {
            float v[4][4];
            #pragma unroll
            for (int t = 0; t < 4; ++t) {
                float4 f = *(const float4*)&x_hsi[((b * 128 + kc + cq * 4 + t) << 12) + l0 + lq * 4];
                v[t][0] = f.x; v[t][1] = f.y; v[t][2] = f.z; v[t][3] = f.w;
            }
            #pragma unroll
            for (int i = 0; i < 4; ++i) {
                unsigned p0 = pk2bf(v[0][i], v[1][i]);
                unsigned p1 = pk2bf(v[2][i], v[3][i]);
                unsigned long long u = (unsigned long long)p0 | ((unsigned long long)p1 << 32);
                *(unsigned long long*)&Abf[(lq * 4 + i) * LSTR + cq * 4] = u;
            }
        }
        // stage B: direct bf16 copy from wtin (256 rows x 8 segs)
        #pragma unroll
        for (int it = 0; it < 4; ++it) {
            int slot = tid + it * 512;
            int r = slot >> 3, seg = slot & 7;
            short8 vb = *(const short8*)&wtin[(size_t)(jbase + r) * 128 + kc + seg * 8];
            *(short8*)&Bbf[r * LSTR + seg * 8] = vb;
        }
        __syncthreads();
        #pragma unroll
        for (int kt = 0; kt < 2; ++kt) {
            short8 af[4], bfr[4];
            #pragma unroll
            for (int mt = 0; mt < 4; ++mt)
                af[mt] = *(const short8*)&Abf[(mbase + mt * 16 + lm) * LSTR + kt * 32 + q * 8];
            #pragma unroll
            for (int nt = 0; nt < 4; ++nt)
                bfr[nt] = *(const short8*)&Bbf[(nbase + nt * 16 + lm) * LSTR + kt * 32 + q * 8];
            #pragma unroll
            for (int mt = 0; mt < 4; ++mt)
                #pragma unroll
                for (int nt = 0; nt < 4; ++nt)
                    acc[mt][nt] = __builtin_amdgcn_mfma_f32_16x16x32_bf16(
                        af[mt], bfr[nt], acc[mt][nt], 0, 0, 0);
        }
    }

    const bool is_xh = (jbase == 0);
    #pragma unroll
    for (int mt = 0; mt < 4; ++mt) {
        #pragma unroll
        for (int r = 0; r < 4; ++r) {
            int row = R0 + mbase + mt * 16 + q * 4 + r;
            #pragma unroll
            for (int nt = 0; nt < 4; ++nt) {
                int col = nbase + nt * 16 + lm;     // 0..255
                float val = acc[mt][nt][r];
                if (is_xh) xhbf[row * 256 + col] = f2bf1(val);
                else       zbf[row * 256 + col]  = f2bf1(silu_fast(val));
            }
        }
    }
}

// ---------------------------------------------------------------------------
// K46 (fused): conv_silu(xh) -> xcb (LDS bf16) -> x_dbl via MFMA -> scan
// pass 1 with h_in=0 that ALSO emits y_local = C.h_local + D*xc (fp16).
// xcbf global copy deleted (nothing downstream needs xc anymore).
// One block = one chunk (32 t x 256 d). grid (NCH, BATCH), block 256.
// ---------------------------------------------------------------------------
__global__ __launch_bounds__(256) void k46_conv_gemm_scan1(
    const unsigned short* __restrict__ xhbf, const float* __restrict__ conv_w,
    const float* __restrict__ conv_b, const unsigned short* __restrict__ wxt,
    const float* __restrict__ W_dt, const float* __restrict__ b_dt,
    const float* __restrict__ A_log, const float* __restrict__ Dvec,
    float* __restrict__ xdbl, __half* __restrict__ ylh,
    float* __restrict__ hend, float* __restrict__ dtsg)
{
    __shared__ float cw0[256], cw1[256], cbs[256];
    __shared__ __align__(16) unsigned short xcb[TCH][YSTR]; // conv tile bf16
    __shared__ __align__(16) float xdl[TCH * 40];           // x_dbl fp32
    const int tid = threadIdx.x;
    const int chunk = blockIdx.x;
    const int b = blockIdx.y;
    const int R0 = b * LSEQ + chunk * TCH;

    cw0[tid] = conv_w[2 * tid];
    cw1[tid] = conv_w[2 * tid + 1];
    cbs[tid] = conv_b[tid];

    // scan constants (issued early; used after the GEMM phase)
    const int d = tid;
    float A[16];
    #pragma unroll
    for (int qq = 0; qq < 4; ++qq) {
        float4 al = *(const float4*)&A_log[d * 16 + qq * 4];
        A[qq*4+0] = -__expf(al.x); A[qq*4+1] = -__expf(al.y);
        A[qq*4+2] = -__expf(al.z); A[qq*4+3] = -__expf(al.w);
    }
    bool fast = true;
    #pragma unroll
    for (int n = 1; n < 16; ++n)
        fast = fast && (fabsf(A[n] - (n + 1) * A[0]) <= 1e-4f * fabsf(A[n]) + 1e-7f);
    float wdt[8];
    #pragma unroll
    for (int r = 0; r < 8; ++r) wdt[r] = W_dt[r * 256 + d];
    const float bdt = b_dt[d];
    const float Dd = Dvec[d];

    __syncthreads();   // cw ready

    // ---- conv + silu: whole 32 x 256 tile -> xcb (bf16, LDS only) ----
    #pragma unroll
    for (int it = 0; it < 8; ++it) {
        int idx = tid + it * 256;            // 32 rows x 64 quads
        int r = idx >> 6, qq = idx & 63;
        int row = R0 + r;
        int dd = qq * 4;
        ushort4 cu = *(const ushort4*)&xhbf[(size_t)row * 256 + dd];
        float cur[4] = {bf2f(cu.x), bf2f(cu.y), bf2f(cu.z), bf2f(cu.w)};
        float pv[4] = {0.f, 0.f, 0.f, 0.f};
        if ((row & 4095) != 0) {
            ushort4 pu = *(const ushort4*)&xhbf[(size_t)(row - 1) * 256 + dd];
            pv[0] = bf2f(pu.x); pv[1] = bf2f(pu.y);
            pv[2] = bf2f(pu.z); pv[3] = bf2f(pu.w);
        }
        float o[4];
        #pragma unroll
        for (int e = 0; e < 4; ++e)
            o[e] = silu_fast(pv[e] * cw0[dd+e] + cur[e] * cw1[dd+e] + cbs[dd+e]);
        unsigned p0 = pk2bf(o[0], o[1]), p1 = pk2bf(o[2], o[3]);
        unsigned long long u = (unsigned long long)p0 | ((unsigned long long)p1 << 32);
        *(unsigned long long*)&xcb[r][dd] = u;
    }
    __syncthreads();

    // ---- x_dbl = xcb @ W_x via MFMA (out 32 x 40, K = 256) ----
    // tiles: wave0: m0 n{0,1}; wave1: m1 n{0,1}; wave2: m0 n{2}; wave3: m1 n{2}
    const int w    = tid >> 6;
    const int lane = tid & 63;
    const int lm   = lane & 15;
    const int q    = lane >> 4;
    {
        const int mt  = w & 1;
        const int nlo = (w < 2) ? 0 : 2;
        const int nn  = (w < 2) ? 2 : 1;
        f32x4 macc[2];
        macc[0] = (f32x4){0.f,0.f,0.f,0.f};
        macc[1] = (f32x4){0.f,0.f,0.f,0.f};
        for (int kc = 0; kc < 256; kc += 32) {
            short8 af = *(const short8*)&xcb[mt * 16 + lm][kc + q * 8];
            #pragma unroll
            for (int t = 0; t < 2; ++t) {
                if (t < nn) {
                    short8 bfr = *(const short8*)&wxt[(size_t)((nlo + t) * 16 + lm) * 256 + kc + q * 8];
                    macc[t] = __builtin_amdgcn_mfma_f32_16x16x32_bf16(
                        af, bfr, macc[t], 0, 0, 0);
                }
            }
        }
        #pragma unroll
        for (int t = 0; t < 2; ++t) {
            if (t < nn) {
                #pragma unroll
                for (int r = 0; r < 4; ++r) {
                    int row = mt * 16 + q * 4 + r;
                    int col = (nlo + t) * 16 + lm;
                    if (col < 40) {
                        float v = macc[t][r];
                        xdl[row * 40 + col] = v;
                        xdbl[(size_t)(R0 + row) * 40 + col] = v;
                    }
                }
            }
        }
    }
    __syncthreads();

    // ---- scan pass 1 (h_in = 0) + y_local emit, all data in LDS ----
    f32x2 h2[8];
    #pragma unroll
    for (int j = 0; j < 8; ++j) h2[j] = (f32x2){0.f, 0.f};
    float dtsum = 0.f;

    #pragma unroll 2
    for (int tt = 0; tt < TCH; ++tt) {
        float xcv = bf2f(xcb[tt][d]);

        float dl[8];
        *(float4*)&dl[0] = *(const float4*)&xdl[tt * 40 + 0];
        *(float4*)&dl[4] = *(const float4*)&xdl[tt * 40 + 4];
        float dtr = bdt;
        #pragma unroll
        for (int r = 0; r < 8; ++r) dtr = fmaf(dl[r], wdt[r], dtr);
        float dtv = softplus_fast(dtr);
        dtsum += dtv;
        float dtx = dtv * xcv;

        float Bv[16], Cv[16];
        *(float4*)&Bv[0]  = *(const float4*)&xdl[tt * 40 + 8];
        *(float4*)&Bv[4]  = *(const float4*)&xdl[tt * 40 + 12];
        *(float4*)&Bv[8]  = *(const float4*)&xdl[tt * 40 + 16];
        *(float4*)&Bv[12] = *(const float4*)&xdl[tt * 40 + 20];
        *(float4*)&Cv[0]  = *(const float4*)&xdl[tt * 40 + 24];
        *(float4*)&Cv[4]  = *(const float4*)&xdl[tt * 40 + 28];
        *(float4*)&Cv[8]  = *(const float4*)&xdl[tt * 40 + 32];
        *(float4*)&Cv[12] = *(const float4*)&xdl[tt * 40 + 36];

        f32x2 dA2[8];
        dA_powers2(dtv, A, fast, dA2);
        f32x2 dtx2 = (f32x2){dtx, dtx};
        f32x2 yv2 = (f32x2){0.f, 0.f};
        #pragma unroll
        for (int j = 0; j < 8; ++j) {
            f32x2 Bt2 = (f32x2){Bv[2*j], Bv[2*j+1]};
            f32x2 Ct2 = (f32x2){Cv[2*j], Cv[2*j+1]};
            h2[j] = dA2[j] * h2[j] + dtx2 * Bt2;
            yv2 = yv2 + h2[j] * Ct2;
        }
        float yv = yv2.x + yv2.y;
        yv = fmaf(Dd, xcv, yv);
        ylh[(size_t)(R0 + tt) * 256 + d] = __float2half(yv);
    }

    const float* hf = (const float*)h2;
    const int base = ((b * NCH + chunk) * 256 + d) * 16;
    #pragma unroll
    for (int qq = 0; qq < 4; ++qq)
        *(float4*)&hend[base + qq * 4] = make_float4(hf[qq*4], hf[qq*4+1], hf[qq*4+2], hf[qq*4+3]);
    dtsg[(b * NCH + chunk) * 256 + d] = dtsum;
}

// ---------------------------------------------------------------------------
// Scan pass 2: sequential combine with P(c) = exp(dtsum(c)*A[n]) on the fly;
// hx: hend -> hin in-place. 8-deep prefetch, NCH/8 = 16 groups.
// grid 128, block 256
// ---------------------------------------------------------------------------
__global__ __launch_bounds__(256) void k7_combine(
    const float* __restrict__ dtsg, const float* __restrict__ A_log,
    float* __restrict__ hx)
{
    const int idx = blockIdx.x * 256 + threadIdx.x;   // b*4096 + d*16 + n
    const int b = idx >> 12;
    const int rem = idx & 4095;
    const int d = rem >> 4, n = rem & 15;
    const float An = -__expf(A_log[d * 16 + n]);
    const int base = b * NCH * 4096 + rem;            // hx index, +4096/chunk
    const int sbase = b * NCH * 256 + d;              // dtsg index, +256/chunk
    float h = 0.f;
    float Sb[8], Eb[8];
    #pragma unroll
    for (int j = 0; j < 8; ++j) {
        Sb[j] = dtsg[sbase + j * 256];
        Eb[j] = hx[base + j * 4096];
    }
    for (int g = 0; g < NCH / 8; ++g) {
        const int o  = base + g * 32768;
        const int so = sbase + g * 2048;
        float Sn[8] = {0,0,0,0,0,0,0,0}, En[8] = {0,0,0,0,0,0,0,0};
        if (g < NCH / 8 - 1) {
            #pragma unroll
            for (int j = 0; j < 8; ++j) {
                Sn[j] = dtsg[so + 2048 + j * 256];
                En[j] = hx[o + 32768 + j * 4096];
            }
        }
        #pragma unroll
        for (int j = 0; j < 8; ++j) {
            hx[o + j * 4096] = h;
            float P = __expf(Sb[j] * An);
            h = fmaf(P, h, Eb[j]);
        }
        #pragma unroll
        for (int j = 0; j < 8; ++j) { Sb[j] = Sn[j]; Eb[j] = En[j]; }
    }
}

// ---------------------------------------------------------------------------
// K89 (fused): correction pass -> Ybf -> MFMA out-GEMM + GN partials.
// y(t) = y_local(t) + sum_n C[t][n] * exp(A_n * cumdt(t)) * h_in[n].
// cumdt monotone + A <= -1  =>  once cumdt > THR the correction is < e^-THR
// and ALL later steps skip it (wave-uniform break). No h recurrence, no B
// operands, no xc read. One block = one chunk (32 t x 256 d).
// grid (NCH, BATCH), block 256. LDS ~17 KB (Ybf only).
// ---------------------------------------------------------------------------
#define CORR_THR 10.0f

__global__ __launch_bounds__(256) void k89_corr_gemm_out(
    const __half* __restrict__ ylh, const float* __restrict__ xdbl,
    const float* __restrict__ W_dt, const float* __restrict__ b_dt,
    const float* __restrict__ A_log, const float* __restrict__ hin,
    const unsigned short* __restrict__ zbf,
    const unsigned short* __restrict__ wtout,
    unsigned short* __restrict__ out_bf, float* __restrict__ part)
{
    __shared__ __align__(16) unsigned short Ybf[TCH][YSTR];    // y tile (rows=l)
    __shared__ float pred[8];
    const int tid = threadIdx.x;
    const int chunk = blockIdx.x;
    const int b = blockIdx.y;
    const int t0 = b * LSEQ + chunk * TCH;

    if (tid < 8) pred[tid] = 0.0f;

    const int d = tid;
    float A[16];
    #pragma unroll
    for (int qq = 0; qq < 4; ++qq) {
        float4 al = *(const float4*)&A_log[d * 16 + qq * 4];
        A[qq*4+0] = -__expf(al.x); A[qq*4+1] = -__expf(al.y);
        A[qq*4+2] = -__expf(al.z); A[qq*4+3] = -__expf(al.w);
    }
    bool fast = true;
    #pragma unroll
    for (int n = 1; n < 16; ++n)
        fast = fast && (fabsf(A[n] - (n + 1) * A[0]) <= 1e-4f * fabsf(A[n]) + 1e-7f);
    float wdt[8];
    #pragma unroll
    for (int r = 0; r < 8; ++r) wdt[r] = W_dt[r * 256 + d];
    const float bdt = b_dt[d];
    const float negA0 = -A[0];                // >= 1 for this problem

    // h_in for this chunk
    f32x2 h2[8];
    {
        const int hbase = ((b * NCH + chunk) * 256 + d) * 16;
        float hf[16];
        #pragma unroll
        for (int qq = 0; qq < 4; ++qq) {
            float4 hv = *(const float4*)&hin[hbase + qq * 4];
            hf[qq*4+0] = hv.x; hf[qq*4+1] = hv.y; hf[qq*4+2] = hv.z; hf[qq*4+3] = hv.w;
        }
        #pragma unroll
        for (int j = 0; j < 8; ++j) h2[j] = (f32x2){hf[2*j], hf[2*j+1]};
    }

    const unsigned short* ylu = (const unsigned short*)ylh;

    // ---- correction loop (active while exp(A*cum) is non-negligible) ----
    float cum = 0.f;
    int tt = 0;
    for (; tt < TCH; ++tt) {
        const int row = t0 + tt;
        const size_t gi = (size_t)row * 256 + d;

        const float* xr = &xdbl[(size_t)row * 40];   // wave-uniform
        float dl[8], Cv[16];
        *(float4*)&dl[0] = *(const float4*)&xr[0];
        *(float4*)&dl[4] = *(const float4*)&xr[4];
        *(float4*)&Cv[0]  = *(const float4*)&xr[24];
        *(float4*)&Cv[4]  = *(const float4*)&xr[28];
        *(float4*)&Cv[8]  = *(const float4*)&xr[32];
        *(float4*)&Cv[12] = *(const float4*)&xr[36];

        float dtr = bdt;
        #pragma unroll
        for (int r = 0; r < 8; ++r) dtr = fmaf(dl[r], wdt[r], dtr);
        cum += softplus_fast(dtr);

        f32x2 P2[8];
        dA_powers2(cum, A, fast, P2);                 // P = exp(A*cum)
        f32x2 cr2 = (f32x2){0.f, 0.f};
        #pragma unroll
        for (int j = 0; j < 8; ++j) {
            f32x2 Ct2 = (f32x2){Cv[2*j], Cv[2*j+1]};
            cr2 = cr2 + Ct2 * (P2[j] * h2[j]);
        }
        unsigned short yu = ylu[gi];
        __half yh;
        __builtin_memcpy(&yh, &yu, 2);
        float y = __half2float(yh) + cr2.x + cr2.y;
        Ybf[tt][d] = f2bf1(y * bf2f(zbf[gi]));

        if (__all(cum * negA0 > CORR_THR)) { ++tt; break; }
    }
    // ---- light tail: correction negligible, just gate + store ----
    for (; tt < TCH; ++tt) {
        const size_t gi = (size_t)(t0 + tt) * 256 + d;
        unsigned short yu = ylu[gi];
        __half yh;
        __builtin_memcpy(&yh, &yu, 2);
        Ybf[tt][d] = f2bf1(__half2float(yh) * bf2f(zbf[gi]));
    }
    __syncthreads();

    // ---- MFMA out-GEMM: out[c][l] = sum_k wtout[c][k] * y[l][k] ----
    // A-frags direct from global wtout (L2-hot); B-frags from Ybf LDS.
    const int w    = tid >> 6;
    const int lane = tid & 63;
    const int lm   = lane & 15;
    const int q    = lane >> 4;
    const int mbase = (w & 1) * 64;           // c-half
    const int nbase = (w >> 1) * 16;          // l-half (of 32)

    f32x4 acc[4];
    #pragma unroll
    for (int i = 0; i < 4; ++i) acc[i] = (f32x4){0.f, 0.f, 0.f, 0.f};

    for (int ks = 0; ks < 256; ks += 32) {
        short8 bfr = *(const short8*)&Ybf[nbase + lm][ks + q * 8];
        #pragma unroll
        for (int mt = 0; mt < 4; ++mt) {
            short8 af = *(const short8*)&wtout[(size_t)(mbase + mt * 16 + lm) * 256 + ks + q * 8];
            acc[mt] = __builtin_amdgcn_mfma_f32_16x16x32_bf16(
                af, bfr, acc[mt], 0, 0, 0);
        }
    }

    const int l0 = chunk * TCH;
    #pragma unroll
    for (int mt = 0; mt < 4; ++mt) {
        #pragma unroll
        for (int r = 0; r < 4; ++r) {
            int c = mbase + mt * 16 + q * 4 + r;
            long obase = (long)(b * 128 + c) * 4096 + l0;
            out_bf[obase + nbase + lm] = f2bf1(acc[mt][r]);
        }
    }

    // fused GroupNorm partial sums (fp32 from accumulators)
    float s0 = 0.f, q0 = 0.f, s1 = 0.f, q1 = 0.f;
    #pragma unroll
    for (int mt = 0; mt < 4; ++mt)
        #pragma unroll
        for (int r = 0; r < 4; ++r) {
            float v = acc[mt][r];
            if (mt < 2) { s0 += v; q0 += v * v; }
            else        { s1 += v; q1 += v * v; }
        }
    #pragma unroll
    for (int off = 32; off > 0; off >>= 1) {
        s0 += __shfl_down(s0, off, 64);
        q0 += __shfl_down(q0, off, 64);
        s1 += __shfl_down(s1, off, 64);
        q1 += __shfl_down(q1, off, 64);
    }
    if (lane == 0) {
        int g0 = mbase >> 5;                  // 0 or 2
        atomicAdd(&pred[g0 * 2],           s0);
        atomicAdd(&pred[g0 * 2 + 1],       q0);
        atomicAdd(&pred[(g0 + 1) * 2],     s1);
        atomicAdd(&pred[(g0 + 1) * 2 + 1], q1);
    }
    __syncthreads();
    if (tid < 8) atomicAdd(&part[b * 8 + tid], pred[tid]);
}

// K10c: apply GN + silu + residual (stat from part; out_bf bf16).
// grid 4096, block 256
__global__ __launch_bounds__(256) void k10c_apply(
    const unsigned short* __restrict__ out_bf, const float* __restrict__ part,
    const float* __restrict__ gamma, const float* __restrict__ beta,
    const float* __restrict__ x_hsi, float* __restrict__ out)
{
    __shared__ float sstat[64];
    if (threadIdx.x < 32) {
        float S = part[threadIdx.x * 2];
        float Q = part[threadIdx.x * 2 + 1];
        const float inv_n = 1.0f / 131072.0f;
        float mean = S * inv_n;
        float var  = Q * inv_n - mean * mean;
        sstat[threadIdx.x * 2]     = mean;
        sstat[threadIdx.x * 2 + 1] = rsqrtf(var + 1e-5f);
    }
    __syncthreads();
    const int idx4 = blockIdx.x * 256 + threadIdx.x;
    const int flat = idx4 * 4;
    const int c = (flat >> 12) & 127;
    const int b = flat >> 19;
    const int g = c >> 5;
    const float mean = sstat[(b * 4 + g) * 2];
    const float inv  = sstat[(b * 4 + g) * 2 + 1];
    const float ga = gamma[c], be = beta[c];
    ushort4 u = *(const ushort4*)&out_bf[flat];
    float4 r = *(const float4*)&x_hsi[flat];
    float vv[4] = {bf2f(u.x), bf2f(u.y), bf2f(u.z), bf2f(u.w)};
    float rr[4] = {r.x, r.y, r.z, r.w};
    float o[4];
    #pragma unroll
    for (int qq = 0; qq < 4; ++qq) {
        float xn = (vv[qq] - mean) * inv;
        float gv = xn * ga + be;
        o[qq] = silu_fast(gv) + rr[qq];
    }
    *(float4*)&out[flat] = make_float4(o[0], o[1], o[2], o[3]);
}

// ---------------------------------------------------------------------------
extern "C" void kernel_launch(void* const* d_in, const int* in_sizes, int n_in,
                              void* d_out, int out_size, void* d_ws, size_t ws_size,
                              hipStream_t stream)
{
    const float* x_hsi  = (const float*)d_in[0];
    const float* W_in   = (const float*)d_in[1];
    const float* conv_w = (const float*)d_in[2];
    const float* conv_b = (const float*)d_in[3];
    const float* W_x    = (const float*)d_in[4];
    const float* W_dt   = (const float*)d_in[5];
    const float* b_dt   = (const float*)d_in[6];
    const float* A_log  = (const float*)d_in[7];
    const float* Dv     = (const float*)d_in[8];
    const float* W_out  = (const float*)d_in[9];
    const float* gnw    = (const float*)d_in[10];
    const float* gnb    = (const float*)d_in[11];

    float* ws = (float*)d_ws;
    unsigned short* xhbf = (unsigned short*)(ws + 0);          // 8,388,608 us
    unsigned short* zbf  = (unsigned short*)(ws + 4194304);    // 8,388,608 us
    float* xdbl   = ws + 8388608;      // 327,680 f
    float* hx     = ws + 8716288;      // 4,194,304 f  (8*128*4096) hend -> hin
    float* dtsg   = ws + 12910592;     // 262,144 f
    __half* ylh   = (__half*)(ws + 13172736);                  // 8,388,608 h
    unsigned short* out_bf = (unsigned short*)(ws + 17367040); // 4,194,304 us
    float* part   = ws + 19464192;     // 64 f
    unsigned short* wtin  = (unsigned short*)(ws + 19464256);  // 65,536 us
    unsigned short* wtout = (unsigned short*)(ws + 19497024);  // 32,768 us
    unsigned short* wxt   = (unsigned short*)(ws + 19513408);  // 12,288 us
    float* outp   = (float*)d_out;

    k0_setup<<<26, 256, 0, stream>>>(W_in, W_out, W_x, wtin, wtout, wxt, part);
    k1_gemm_in<<<dim3(256, 2), 512, 0, stream>>>(x_hsi, wtin, xhbf, zbf);
    k46_conv_gemm_scan1<<<dim3(NCH, BATCH), 256, 0, stream>>>(
        xhbf, conv_w, conv_b, wxt, W_dt, b_dt, A_log, Dv, xdbl, ylh, hx, dtsg);
    k7_combine<<<128, 256, 0, stream>>>(dtsg, A_log, hx);
    k89_corr_gemm_out<<<dim3(NCH, BATCH), 256, 0, stream>>>(
        ylh, xdbl, W_dt, b_dt, A_log, hx, zbf, wtout, out_bf, part);
    k10c_apply<<<4096, 256, 0, stream>>>(out_bf, part, gnw, gnb, x_hsi, outp);
}